// Round 12
// baseline (569.697 us; speedup 1.0000x reference)
//
#include <hip/hip_runtime.h>
#include <hip/hip_bf16.h>
#include <stdint.h>

// Problem constants (fixed by reference setup_inputs)
constexpr int HEADS = 8;
constexpr int B = 4;
constexpr int BH = B * HEADS;   // 32
constexpr int T = 16384;
constexpr int DH = 64;
constexpr int NB = 128;          // MAX_BUCKETS
constexpr int DIM = 128;         // 2*DH
constexpr float EPS = 1e-6f;
constexpr float INV_TEMP = 1.0f / 0.7f;

constexpr int CHUNK = 1024;      // rows per block
constexpr int SPAN = 16;         // max buckets a chunk may span (guarded)
constexpr int CPAD = SPAN * DIM + 1;  // 2049 floats: odd stride -> bank shift 1/copy

typedef float v4f __attribute__((ext_vector_type(4)));

// 8 x global_load_dwordx4 (1 KB per wave per instr), 4 address pairs with
// offsets {0,2048}; single vmcnt(0). Guarantees 8 KB in flight per wave.
#define LOAD8(A0, A1, A2, A3)                                               \
  asm volatile(                                                             \
      "global_load_dwordx4 %[o0], %[a0], off\n\t"                           \
      "global_load_dwordx4 %[o1], %[a0], off offset:2048\n\t"               \
      "global_load_dwordx4 %[o2], %[a1], off\n\t"                           \
      "global_load_dwordx4 %[o3], %[a1], off offset:2048\n\t"               \
      "global_load_dwordx4 %[o4], %[a2], off\n\t"                           \
      "global_load_dwordx4 %[o5], %[a2], off offset:2048\n\t"               \
      "global_load_dwordx4 %[o6], %[a3], off\n\t"                           \
      "global_load_dwordx4 %[o7], %[a3], off offset:2048\n\t"               \
      "s_waitcnt vmcnt(0)"                                                  \
      : [o0] "=&v"(v0), [o1] "=&v"(v1), [o2] "=&v"(v2), [o3] "=&v"(v3),     \
        [o4] "=&v"(v4), [o5] "=&v"(v5), [o6] "=&v"(v6), [o7] "=&v"(v7)      \
      : [a0] "v"(A0), [a1] "v"(A1), [a2] "v"(A2), [a3] "v"(A3)              \
      : "memory")

// ---------------------------------------------------------------------------
// K1: bucket sums, DRAM-friendly. One block per (bh, 1024-row chunk).
// Waves 0-1 sweep q contiguously, waves 2-3 sweep k (1 KB/instr, sequential).
// Branch-free accumulate: LDS atomicAdd into per-sub bucket tables
// (4 copies, odd stride). Flush with global atomicAdd over the chunk's span.
// ---------------------------------------------------------------------------
__global__ __launch_bounds__(256) void k_bucketsum(
    const float* __restrict__ q, const float* __restrict__ k,
    const int* __restrict__ seg, float* __restrict__ x) {
  const int bh = blockIdx.x >> 4;        // 512 blocks: bh * 16 chunks
  const int c = blockIdx.x & 15;
  const int b = bh >> 3;
  const int t0 = c * CHUNK;
  const int tid = threadIdx.x;

  __shared__ int ids[CHUNK];             // 4 KB
  __shared__ float sums[4 * CPAD];       // ~32 KB

  for (int i = tid; i < CHUNK; i += 256) ids[i] = seg[(size_t)b * T + t0 + i];
  for (int i = tid; i < 4 * CPAD; i += 256) sums[i] = 0.f;
  __syncthreads();

  const int bmin = ids[0];
  const int span = ids[CHUNK - 1] - bmin + 1;

  const int w = tid >> 6;                // wave 0..3
  const int lane = tid & 63;
  const int sub = lane >> 4;             // 0..3
  const int cc = lane & 15;              // float4 col chunk
  const bool isq = (w < 2);
  const int slot = (w & 1) * 4 + sub;    // row slot 0..7
  const float* srcb = (isq ? q : k) + (size_t)bh * T * DH + (size_t)t0 * DH;
  float* copy = &sums[sub * CPAD];
  const int coloff = (isq ? 0 : DH) + cc * 4;

  if (span <= SPAN) {
    // per-wave byte base: row = i*8 + slot, addr = srcb + row*256 + cc*16
    const uint64_t base =
        (uint64_t)(uintptr_t)srcb + (uint64_t)slot * 256 + (uint64_t)cc * 16;
    for (int i0 = 0; i0 < CHUNK / 8; i0 += 8) {
      const uint64_t a0 = base + (uint64_t)i0 * 2048;
      const uint64_t a1 = a0 + 4096;
      const uint64_t a2 = a0 + 8192;
      const uint64_t a3 = a0 + 12288;
      v4f v0, v1, v2, v3, v4, v5, v6, v7;
      LOAD8(a0, a1, a2, a3);
      v4f vv[8] = {v0, v1, v2, v3, v4, v5, v6, v7};
#pragma unroll
      for (int u = 0; u < 8; u++) {
        const int row = (i0 + u) * 8 + slot;
        const int id = ids[row] - bmin;
        float* d = copy + id * DIM + coloff;
        atomicAdd(d + 0, vv[u].x);
        atomicAdd(d + 1, vv[u].y);
        atomicAdd(d + 2, vv[u].z);
        atomicAdd(d + 3, vv[u].w);
      }
    }
  } else {
    // fallback (not expected for this data): direct global atomics
    for (int i = 0; i < CHUNK / 8; i++) {
      const int row = i * 8 + slot;
      const float4 v = *(const float4*)(srcb + (size_t)row * DH + cc * 4);
      float* d = x + ((size_t)bh * NB + ids[row]) * DIM + coloff;
      atomicAdd(d + 0, v.x);
      atomicAdd(d + 1, v.y);
      atomicAdd(d + 2, v.z);
      atomicAdd(d + 3, v.w);
    }
  }
  __syncthreads();

  if (span <= SPAN) {
    const int total = span * DIM;
    float* xp = x + ((size_t)bh * NB + bmin) * DIM;
    for (int i = tid; i < total; i += 256) {
      const float vsum = sums[0 * CPAD + i] + sums[1 * CPAD + i] +
                         sums[2 * CPAD + i] + sums[3 * CPAD + i];
      atomicAdd(&xp[i], vsum);
    }
  }
}

// ---------------------------------------------------------------------------
// K2a: R = relu(x @ W), r0 = (log(R+eps) + gumbel)/temp. One block per
// (bh, 16-row chunk). x rows staged in LDS; W streamed from L1/L2.
// ---------------------------------------------------------------------------
__global__ __launch_bounds__(256) void k_matmul(
    const float* __restrict__ x, const float* __restrict__ linear,
    const float* __restrict__ gumbel, float* __restrict__ r0) {
  const int bh = blockIdx.y;
  const int n0 = blockIdx.x * 16;
  const int h = bh & 7;                  // bh % HEADS
  const int tid = threadIdx.x;

  __shared__ float xs[16][DIM];          // 8 KB

  const float4* xp = (const float4*)(x + ((size_t)bh * NB + n0) * DIM);
  for (int i = tid; i < 16 * 32; i += 256) {
    const float4 v = xp[i];
    const int n = i >> 5, d4 = i & 31;
    xs[n][d4 * 4 + 0] = v.x;
    xs[n][d4 * 4 + 1] = v.y;
    xs[n][d4 * 4 + 2] = v.z;
    xs[n][d4 * 4 + 3] = v.w;
  }
  __syncthreads();

  const int mt = tid & 31;               // output col float4
  const int rp = tid >> 5;               // 0..7 row pair
  const int ra = rp * 2;

  float4 a0 = make_float4(0.f, 0.f, 0.f, 0.f);
  float4 a1 = make_float4(0.f, 0.f, 0.f, 0.f);
  const float4* Wp = (const float4*)(linear + (size_t)h * DIM * NB);
  for (int d4 = 0; d4 < 32; d4++) {
    const float4 xv0 = *(const float4*)&xs[ra][d4 * 4];
    const float4 xv1 = *(const float4*)&xs[ra + 1][d4 * 4];
    const float4 w0 = Wp[(d4 * 4 + 0) * 32 + mt];
    const float4 w1 = Wp[(d4 * 4 + 1) * 32 + mt];
    const float4 w2 = Wp[(d4 * 4 + 2) * 32 + mt];
    const float4 w3 = Wp[(d4 * 4 + 3) * 32 + mt];
    a0.x += xv0.x * w0.x + xv0.y * w1.x + xv0.z * w2.x + xv0.w * w3.x;
    a0.y += xv0.x * w0.y + xv0.y * w1.y + xv0.z * w2.y + xv0.w * w3.y;
    a0.z += xv0.x * w0.z + xv0.y * w1.z + xv0.z * w2.z + xv0.w * w3.z;
    a0.w += xv0.x * w0.w + xv0.y * w1.w + xv0.z * w2.w + xv0.w * w3.w;
    a1.x += xv1.x * w0.x + xv1.y * w1.x + xv1.z * w2.x + xv1.w * w3.x;
    a1.y += xv1.x * w0.y + xv1.y * w1.y + xv1.z * w2.y + xv1.w * w3.y;
    a1.z += xv1.x * w0.z + xv1.y * w1.z + xv1.z * w2.z + xv1.w * w3.z;
    a1.w += xv1.x * w0.w + xv1.y * w1.w + xv1.z * w2.w + xv1.w * w3.w;
  }

  const float4* gp = (const float4*)(gumbel + ((size_t)bh * NB + n0) * NB);
  float4* op = (float4*)(r0 + ((size_t)bh * NB + n0) * NB);

  auto xform = [](float a, float u) {
    const float R = fmaxf(a, 0.f);
    const float g = -__logf(-__logf(u + EPS) + EPS);
    return (__logf(R + EPS) + g) * INV_TEMP;
  };
  {
    const float4 u = gp[(size_t)ra * 32 + mt];
    float4 o;
    o.x = xform(a0.x, u.x); o.y = xform(a0.y, u.y);
    o.z = xform(a0.z, u.z); o.w = xform(a0.w, u.w);
    op[(size_t)ra * 32 + mt] = o;
  }
  {
    const float4 u = gp[(size_t)(ra + 1) * 32 + mt];
    float4 o;
    o.x = xform(a1.x, u.x); o.y = xform(a1.y, u.y);
    o.z = xform(a1.z, u.z); o.w = xform(a1.w, u.w);
    op[(size_t)(ra + 1) * 32 + mt] = o;
  }
}

// ---------------------------------------------------------------------------
// K2b: 8 Sinkhorn iterations + exp. One block (512 threads) per bh.
// Row state in REGISTERS: thread (row=tid>>2, qp=tid&3) owns r[row][qp*32+j].
// ---------------------------------------------------------------------------
__global__ __launch_bounds__(512) void k_sinkhorn(
    const float* __restrict__ r0, float* __restrict__ out) {
  const int bh = blockIdx.x;
  const int tid = threadIdx.x;

  __shared__ float img[NB * (NB + 1)];   // stride 129, 66 KB
  __shared__ float lse_c[NB];

  const int row = tid >> 2;              // 0..127 (col index in col pass)
  const int qp = tid & 3;                // quarter

  float rr[32];
  {
    const float4* rp =
        (const float4*)(r0 + (size_t)bh * NB * NB + row * NB + qp * 32);
#pragma unroll
    for (int u = 0; u < 8; u++) {
      const float4 v = rp[u];
      rr[4 * u + 0] = v.x; rr[4 * u + 1] = v.y;
      rr[4 * u + 2] = v.z; rr[4 * u + 3] = v.w;
    }
  }

  for (int it = 0; it < 8; it++) {
    // ---- row logsumexp (pure registers + 2 shfl) ----
    float m = rr[0];
#pragma unroll
    for (int j = 1; j < 32; j++) m = fmaxf(m, rr[j]);
    m = fmaxf(m, __shfl_xor(m, 1));
    m = fmaxf(m, __shfl_xor(m, 2));
    float s = 0.f;
#pragma unroll
    for (int j = 0; j < 32; j++) s += __expf(rr[j] - m);
    s += __shfl_xor(s, 1);
    s += __shfl_xor(s, 2);
    const float lse = m + __logf(s);
#pragma unroll
    for (int j = 0; j < 32; j++) rr[j] -= lse;

    // ---- publish row-normalized values ----
#pragma unroll
    for (int j = 0; j < 32; j++) img[row * (NB + 1) + qp * 32 + j] = rr[j];
    __syncthreads();

    // ---- column logsumexp: col c = row; rows n = qp*32 + stagger(j) ----
    float tmp[32];
#pragma unroll
    for (int j = 0; j < 32; j++) {
      const int n = qp * 32 + ((j + qp * 8) & 31);
      tmp[j] = img[n * (NB + 1) + row];
    }
    float cm = tmp[0];
#pragma unroll
    for (int j = 1; j < 32; j++) cm = fmaxf(cm, tmp[j]);
    cm = fmaxf(cm, __shfl_xor(cm, 1));
    cm = fmaxf(cm, __shfl_xor(cm, 2));
    float cs = 0.f;
#pragma unroll
    for (int j = 0; j < 32; j++) cs += __expf(tmp[j] - cm);
    cs += __shfl_xor(cs, 1);
    cs += __shfl_xor(cs, 2);
    if (qp == 0) lse_c[row] = cm + __logf(cs);
    __syncthreads();

    // ---- subtract column lse (broadcast reads) ----
#pragma unroll
    for (int j = 0; j < 32; j++) rr[j] -= lse_c[qp * 32 + j];
  }

  // ---- output exp(r) ----
  {
    float4* op = (float4*)(out + (size_t)bh * NB * NB + row * NB + qp * 32);
#pragma unroll
    for (int u = 0; u < 8; u++) {
      float4 v;
      v.x = __expf(rr[4 * u + 0]);
      v.y = __expf(rr[4 * u + 1]);
      v.z = __expf(rr[4 * u + 2]);
      v.w = __expf(rr[4 * u + 3]);
      op[u] = v;
    }
  }
}

// ---------------------------------------------------------------------------
extern "C" void kernel_launch(void* const* d_in, const int* in_sizes, int n_in,
                              void* d_out, int out_size, void* d_ws, size_t ws_size,
                              hipStream_t stream) {
  const float* q = (const float*)d_in[0];
  const float* k = (const float*)d_in[1];
  const float* linear = (const float*)d_in[2];   // (1, 8, 128, 128)
  const int* seg = (const int*)d_in[3];          // (4, 16384)
  const float* gum = (const float*)d_in[4];      // (32, 128, 128)
  float* out = (float*)d_out;                    // (32, 128, 128) f32

  float* x = (float*)d_ws;                       // (32, 128, 128) f32 scratch
  float* r0 = out;                               // stage r0 in d_out (2 MB)

  hipMemsetAsync(x, 0, (size_t)BH * NB * DIM * sizeof(float), stream);

  k_bucketsum<<<BH * (T / CHUNK), 256, 0, stream>>>(q, k, seg, x);

  dim3 g2(8, BH);
  k_matmul<<<g2, 256, 0, stream>>>(x, linear, gum, r0);

  k_sinkhorn<<<BH, 512, 0, stream>>>(r0, out);
}